// Round 6
// baseline (88.338 us; speedup 1.0000x reference)
//
#include <hip/hip_runtime.h>
#include <hip/hip_fp16.h>

#define TBINS 256
#define RPB   32         // rows per block in row_kernel (16 waves x 2 rows)
#define NTHR  1024
#define NHIST 8          // LDS histograms in agg kernel (2 waves share one)
#define EPS_F 1e-7f
#define INV_SIGMA 2.0f   // 1/0.5

// ============ K1: per-row softmax/cdf -> WT (f16, transposed), aux pack, nll partials ============
__global__ __launch_bounds__(NTHR) void row_kernel(
    const float* __restrict__ hz, const int* __restrict__ dur,
    const int* __restrict__ ev,  const int* __restrict__ lab,
    __half* __restrict__ WT, __half* __restrict__ rowAh,
    unsigned* __restrict__ aux, float* __restrict__ nllpart,
    float* __restrict__ accR, int* __restrict__ done, int n)
{
    __shared__ float trs[RPB][261];   // pad 261: conflict-free transpose
    __shared__ float nllred[RPB];

    const int tid  = threadIdx.x;
    const int wid  = tid >> 6;
    const int lane = tid & 63;

    if (blockIdx.x == 0 && tid == 0) { *accR = 0.f; *done = 0; }

    #pragma unroll
    for (int r = 0; r < 2; ++r) {
        const int lrow = wid * 2 + r;
        const int row  = blockIdx.x * RPB + lrow;
        const bool act = row < n;
        const int rrow = act ? row : 0;

        const float4 v = ((const float4*)(hz + (size_t)rrow * TBINS))[lane];

        float m = fmaxf(fmaxf(v.x, v.y), fmaxf(v.z, v.w));
        #pragma unroll
        for (int off = 32; off; off >>= 1) m = fmaxf(m, __shfl_xor(m, off));
        const float gamma = fmaxf(m, 0.0f);        // phi has padded 0 column

        const float e0 = expf(v.x - gamma), e1 = expf(v.y - gamma);
        const float e2 = expf(v.z - gamma), e3 = expf(v.w - gamma);
        const float local = e0 + e1 + e2 + e3;

        float pre = local;
        #pragma unroll
        for (int off = 1; off < 64; off <<= 1) {
            float tv = __shfl_up(pre, off);
            if (lane >= off) pre += tv;
        }
        const float excl  = pre - local;
        const float total = __shfl(pre, 63);
        const float sum_  = total + expf(-gamma);  // padded column exp(0-gamma)
        const float c0 = excl + e0, c1 = c0 + e1, c2 = c1 + e2, c3 = c2 + e3;

        const int L = lab[rrow];
        const int e = ev[rrow];
        const int d = dur[rrow];
        const int sel = L & 3;
        const float csel  = (sel == 0) ? c0  : (sel == 1) ? c1  : (sel == 2) ? c2  : c3;
        const float phsel = (sel == 0) ? v.x : (sel == 1) ? v.y : (sel == 2) ? v.z : v.w;
        const float cum_at = __shfl(csel, L >> 2);
        const float phi_at = __shfl(phsel, L >> 2);   // no global reload
        const float inv = 1.0f / sum_;

        float4 w;
        w.x = expf(c0 * inv * INV_SIGMA);
        w.y = expf(c1 * inv * INV_SIGMA);
        w.z = expf(c2 * inv * INV_SIGMA);
        w.w = expf(c3 * inv * INV_SIGMA);
        *(float4*)&trs[lrow][4 * lane] = w;

        if (lane == 0) {
            float nll_i = 0.f;
            if (act) {
                const float evf = (float)e;
                const float p1 = (phi_at - gamma) * evf;
                const float p2 = -logf(fmaxf(sum_, 0.f) + EPS_F);
                const float p3 = logf(fmaxf(sum_ - cum_at, 0.f) + EPS_F) * (1.f - evf);
                nll_i = -(p1 + p2 + p3);
                const float a_i = e ? expf(-(cum_at * inv) * INV_SIGMA) : 0.f;
                rowAh[row] = __float2half(a_i);
                aux[row] = (unsigned)d | ((unsigned)L << 8) | ((unsigned)(e != 0) << 16);
            }
            nllred[lrow] = nll_i;
        }
    }
    __syncthreads();

    if (tid == 0) {
        float s = 0.f;
        #pragma unroll
        for (int k = 0; k < RPB; ++k) s += nllred[k];
        nllpart[blockIdx.x] = s;
    }

    // transpose out: per t, 8 threads cover 32 rows -> 64B contiguous stores
    #pragma unroll
    for (int k = 0; k < 2; ++k) {
        const int t = (tid >> 3) + 128 * k;
        const int j = tid & 7;
        const int i0 = blockIdx.x * RPB + 4 * j;
        if (i0 + 3 < n) {
            ushort4 p;
            p.x = __half_as_ushort(__float2half(trs[4 * j + 0][t]));
            p.y = __half_as_ushort(__float2half(trs[4 * j + 1][t]));
            p.z = __half_as_ushort(__float2half(trs[4 * j + 2][t]));
            p.w = __half_as_ushort(__float2half(trs[4 * j + 3][t]));
            *(ushort4*)&WT[(size_t)t * n + i0] = p;
        }
    }
}

// ============ K2: per-t histogram + suffix scan (LDS) + rank gather + finalize ============
__global__ __launch_bounds__(NTHR) void agg_rank_kernel(
    const __half* __restrict__ WT, const unsigned* __restrict__ aux,
    const __half* __restrict__ rowAh, const float* __restrict__ nllpart,
    float* __restrict__ accR, int* __restrict__ done,
    float* __restrict__ out, int n, int nblk1)
{
    __shared__ float hist[NHIST][512];   // 16 KB; bin = d + (ev<<8)
    __shared__ float comb[512];
    __shared__ float Brow[TBINS];
    __shared__ float red[16];
    __shared__ int lastflag;

    const int t    = blockIdx.x;
    const int tid  = threadIdx.x;
    const int wid  = tid >> 6;
    const int lane = tid & 63;

    for (int i = tid; i < NHIST * 512; i += NTHR) ((float*)hist)[i] = 0.f;
    __syncthreads();

    // histogram: 8 contiguous elements per thread; keep aux words in registers
    const __half* w = WT + (size_t)t * n;
    const int i0 = tid * 8;
    const bool full = (i0 + 7 < n);
    unsigned ax[8];
    if (full) {
        const ushort4 ha = *(const ushort4*)&w[i0];
        const ushort4 hb = *(const ushort4*)&w[i0 + 4];
        const uint4 xa = *(const uint4*)&aux[i0];
        const uint4 xb = *(const uint4*)&aux[i0 + 4];
        ax[0] = xa.x; ax[1] = xa.y; ax[2] = xa.z; ax[3] = xa.w;
        ax[4] = xb.x; ax[5] = xb.y; ax[6] = xb.z; ax[7] = xb.w;
        const unsigned short hs[8] = { ha.x, ha.y, ha.z, ha.w, hb.x, hb.y, hb.z, hb.w };
        float* hp = hist[wid >> 1];
        #pragma unroll
        for (int k = 0; k < 8; ++k) {
            const int bin = (int)(ax[k] & 255u) | ((int)((ax[k] >> 16) & 1u) << 8);
            atomicAdd(&hp[bin], __half2float(__ushort_as_half(hs[k])));
        }
    } else {
        for (int i = i0; i < n; ++i) {
            const unsigned x = aux[i];
            const int bin = (int)(x & 255u) | ((int)((x >> 16) & 1u) << 8);
            atomicAdd(&hist[wid >> 1][bin], __half2float(w[i]));
        }
    }
    __syncthreads();

    // combine NHIST histograms
    if (tid < 512) {
        float s = 0.f;
        #pragma unroll
        for (int k = 0; k < NHIST; ++k) s += hist[k][tid];
        comb[tid] = s;
    }
    __syncthreads();

    // single-wave suffix scan: G[d] = comb[d] + comb[d+256]; B = suffix(G) + G0
    if (tid < 64) {
        const int d0 = tid * 4;
        const float g0 = comb[d0 + 0] + comb[d0 + 256];
        const float g1 = comb[d0 + 1] + comb[d0 + 257];
        const float g2 = comb[d0 + 2] + comb[d0 + 258];
        const float g3 = comb[d0 + 3] + comb[d0 + 259];
        const float c0 = g0, c1 = c0 + g1, c2 = c1 + g2, c3 = c2 + g3;
        float pre = c3;
        #pragma unroll
        for (int off = 1; off < 64; off <<= 1) {
            float tv = __shfl_up(pre, off);
            if (tid >= off) pre += tv;
        }
        const float excl = pre - c3;
        const float tot  = __shfl(pre, 63);
        Brow[d0 + 0] = (tot - (excl + c0)) + comb[d0 + 0];
        Brow[d0 + 1] = (tot - (excl + c1)) + comb[d0 + 1];
        Brow[d0 + 2] = (tot - (excl + c2)) + comb[d0 + 2];
        Brow[d0 + 3] = (tot - (excl + c3)) + comb[d0 + 3];
    }
    __syncthreads();

    // rank gather for rows with lab == t (aux already in registers)
    float val = 0.f;
    if (full) {
        #pragma unroll
        for (int k = 0; k < 8; ++k) {
            if ((int)((ax[k] >> 8) & 255u) == t) {
                const float a = __half2float(rowAh[i0 + k]);   // 0 when ev==0
                if (a != 0.f) val += a * Brow[ax[k] & 255u];
            }
        }
    } else {
        for (int i = i0; i < n; ++i) {
            const unsigned x = aux[i];
            if ((int)((x >> 8) & 255u) == t) {
                const float a = __half2float(rowAh[i]);
                if (a != 0.f) val += a * Brow[x & 255u];
            }
        }
    }
    #pragma unroll
    for (int off = 32; off; off >>= 1) val += __shfl_xor(val, off);
    if (lane == 0) red[wid] = val;
    __syncthreads();

    if (tid == 0) {
        float s = 0.f;
        #pragma unroll
        for (int k = 0; k < 16; ++k) s += red[k];
        atomicAdd(accR, s);
        __threadfence();
        const int old = atomicAdd(done, 1);
        lastflag = (old == (int)gridDim.x - 1) ? 1 : 0;
    }
    __syncthreads();

    // last block finalizes: reduce nll partials + combine
    if (lastflag) {
        float s = (tid < nblk1) ? nllpart[tid] : 0.f;
        #pragma unroll
        for (int off = 32; off; off >>= 1) s += __shfl_xor(s, off);
        if (lane == 0) red[wid] = s;
        __syncthreads();
        if (tid == 0) {
            float S = 0.f;
            #pragma unroll
            for (int k = 0; k < 16; ++k) S += red[k];
            __threadfence();
            const float R = atomicAdd(accR, 0.0f);   // coherent read
            const double nll = (double)S / (double)n;
            const double rl  = (double)R / ((double)n * (double)n);
            out[0] = (float)(0.5 * nll + 0.5 * rl);
        }
    }
}

extern "C" void kernel_launch(void* const* d_in, const int* in_sizes, int n_in,
                              void* d_out, int out_size, void* d_ws, size_t ws_size,
                              hipStream_t stream) {
    const float* hz  = (const float*)d_in[0];
    const int*   dur = (const int*)d_in[1];
    const int*   ev  = (const int*)d_in[2];
    const int*   lab = (const int*)d_in[3];
    float* out = (float*)d_out;

    const int n = in_sizes[1];                   // 8192
    const int nblk1 = (n + RPB - 1) / RPB;       // 256

    __half*   WT      = (__half*)d_ws;           // [TBINS][n] f16 (4 MB)
    __half*   rowAh   = WT + (size_t)TBINS * n;  // [n] f16
    unsigned* aux     = (unsigned*)(rowAh + n);  // [n] packed {dur | lab<<8 | ev<<16}
    float*    nllpart = (float*)(aux + n);       // [nblk1]
    float*    accR    = nllpart + nblk1;         // rank accumulator
    int*      done    = (int*)(accR + 1);        // completion counter

    row_kernel<<<nblk1, NTHR, 0, stream>>>(hz, dur, ev, lab, WT, rowAh, aux,
                                           nllpart, accR, done, n);
    agg_rank_kernel<<<TBINS, NTHR, 0, stream>>>(WT, aux, rowAh, nllpart,
                                                accR, done, out, n, nblk1);
}